// Round 1
// baseline (622.001 us; speedup 1.0000x reference)
//
#include <hip/hip_runtime.h>
#include <stdint.h>

// out = x @ dequant(W)^T + bias
// x: [M,K] fp32 (M=B*S=8192), W_q: [N,K] int32 codes in [0,4),
// scale/zp: [N,K/G] fp32 (G=64), bias: [N] fp32, out: [M,N] fp32.
//
// R3: replace the 128x128 2-barrier-drain GEMM (m97-structure, 841 TF,
// MfmaUtil 38%) with a 256x256 / BK=32 / 8-wave kernel using a 4-deep LDS
// ring staged 3 K-tiles ahead via global_load_lds + counted s_waitcnt
// vmcnt(12) + raw s_barrier (loads stay in flight across barriers), with
// s_setprio around the two 16-MFMA phases. Same proven (row>>1)&3 LDS
// chunk swizzle on both write (pre-swizzled global source) and read sides.
// XCD-aware block swizzle (nwg=512 %8==0, bijective).

typedef __attribute__((ext_vector_type(4))) float  f32x4;
typedef __attribute__((ext_vector_type(4))) int    i32x4;
typedef __attribute__((ext_vector_type(8))) __bf16 bf16x8;
typedef __attribute__((ext_vector_type(4))) unsigned short u16x4;

__device__ __forceinline__ unsigned short f2bf(float f) {
  unsigned u = __builtin_bit_cast(unsigned, f);
  u += 0x7fffu + ((u >> 16) & 1u);   // round-to-nearest-even
  return (unsigned short)(u >> 16);
}

__device__ __forceinline__ void async16(const void* g, void* l) {
  __builtin_amdgcn_global_load_lds(
      (const __attribute__((address_space(1))) unsigned int*)g,
      (__attribute__((address_space(3))) unsigned int*)l, 16, 0, 0);
}

// ---------------- fused prepass: x->bf16 and dequant W->bf16 ----------------
// (unchanged from R2 — left alone this round so next round's top-5 exposes
//  its true cost once the GEMM drops below it)
__global__ __launch_bounds__(256) void prep_kernel(
    const float* __restrict__ x, unsigned short* __restrict__ xb, int xchunks,
    const int* __restrict__ wq, const float* __restrict__ scale,
    const float* __restrict__ zp, unsigned short* __restrict__ wb,
    int wchunks, int K, int G) {
  int xblocks = (xchunks + 255) >> 8;
  if ((int)blockIdx.x < xblocks) {
    int i = blockIdx.x * 256 + threadIdx.x;
    if (i >= xchunks) return;
    f32x4 a = ((const f32x4*)x)[i];
    u16x4 o;
    o[0] = f2bf(a[0]); o[1] = f2bf(a[1]); o[2] = f2bf(a[2]); o[3] = f2bf(a[3]);
    *(u16x4*)(xb + (size_t)i * 4) = o;
  } else {
    int i = (blockIdx.x - xblocks) * 256 + threadIdx.x;
    if (i >= wchunks) return;
    int k4 = i * 4;
    int n = k4 / K, kk = k4 % K;
    int ng = K / G;
    int g = kk / G;
    float s = scale[(size_t)n * ng + g];
    float b = -zp[(size_t)n * ng + g] * s;   // w = q*s + b
    i32x4 qv = ((const i32x4*)wq)[i];
    u16x4 o;
    o[0] = f2bf((float)qv[0] * s + b); o[1] = f2bf((float)qv[1] * s + b);
    o[2] = f2bf((float)qv[2] * s + b); o[3] = f2bf((float)qv[3] * s + b);
    *(u16x4*)(wb + (size_t)i * 4) = o;
  }
}

// ---------------- main GEMM: C[M,N] = A[M,K] * B[N,K]^T + bias ----------------
#define BM 256
#define BN 256
#define BK 32
#define NBUF 4

__global__ __launch_bounds__(512, 2) void gemm_bt_kernel(
    const unsigned short* __restrict__ A,   // M x K bf16
    const unsigned short* __restrict__ B,   // N x K bf16
    const float* __restrict__ bias,
    float* __restrict__ C, int M, int N, int K) {
  // 4-deep ring: 4 x 256 x 32 bf16 per operand = 64 KB each, 128 KB total.
  __shared__ unsigned short As[NBUF * BM * BK];
  __shared__ unsigned short Bs[NBUF * BM * BK];

  const int tid  = threadIdx.x;
  const int lane = tid & 63;
  const int wave = tid >> 6;                // 8 waves: 2 (M) x 4 (N)
  const int wm = wave >> 2, wn = wave & 3;  // wave tile: 128 (M) x 64 (N)
  const int q = lane >> 4, r = lane & 15;   // MFMA k-group / row-in-16

  // XCD-aware bijective swizzle: 64 consecutive tiles per XCD (nwg%8==0).
  int id = blockIdx.x;
  {
    int nwg = gridDim.x;
    if ((nwg & 7) == 0) id = (id & 7) * (nwg >> 3) + (id >> 3);
  }
  const int nbx = N / BN;
  const int m0 = (id / nbx) * BM;
  const int n0 = (id % nbx) * BN;

  // Staging: global_load_lds forces LDS dest = wave base + lane*16B, i.e.
  // thread tid owns LDS slot (row = tid>>2, chunk = tid&3) of a 128-row
  // block. Swizzle: stored chunk s of row holds GLOBAL chunk s ^ ((row>>1)&3)
  // -> pre-swizzle the global source address, keep LDS dest linear.
  const int srow = tid >> 2;                      // 0..127
  const int gch  = (tid & 3) ^ ((tid >> 3) & 3);  // == (tid&3) ^ ((srow>>1)&3)
  const unsigned short* aG = A + (size_t)(m0 + srow) * K + gch * 8;
  const unsigned short* bG = B + (size_t)(n0 + srow) * K + gch * 8;
  const size_t rowblk = (size_t)128 * K;          // second 128-row block

  // Read side: global chunk q of row lives at stored chunk q ^ ((row>>1)&3);
  // all frag rows are base16 + r with base16 % 16 == 0, so key = (r>>1)&3.
  const int s0   = (q ^ ((r >> 1) & 3)) * 8;      // element offset in row
  const int aOff = (wm * 128 + r) * BK + s0;      // + i*16*BK
  const int bOff = (wn * 64  + r) * BK + s0;      // + j*16*BK

  f32x4 acc[8][4] = {};
  const int NT = K / BK;

#define STAGE(bi, kk) { \
    unsigned short* al = As + (bi) * (BM * BK) + tid * 8; \
    unsigned short* bl = Bs + (bi) * (BM * BK) + tid * 8; \
    async16(aG + (kk), al);  async16(aG + rowblk + (kk), al + 4096); \
    async16(bG + (kk), bl);  async16(bG + rowblk + (kk), bl + 4096); }

  // Prologue: fill 3 ring slots (12 loads in flight, 4 per tile).
  STAGE(0, 0)
  if (NT > 1) STAGE(1, BK)
  if (NT > 2) STAGE(2, 2 * BK)

#pragma unroll 1
  for (int t = 0; t < NT; ++t) {
    // Issue next prefetch first (3-tile lead), then wait only until tile t's
    // 4 loads (issued 3 iterations ago) have landed — 12 stay in flight.
    if (t + 3 < NT) STAGE((t + 3) & 3, (t + 3) * BK)
    if (t + 3 < NT)      asm volatile("s_waitcnt vmcnt(12)" ::: "memory");
    else if (t + 2 < NT) asm volatile("s_waitcnt vmcnt(8)"  ::: "memory");
    else if (t + 1 < NT) asm volatile("s_waitcnt vmcnt(4)"  ::: "memory");
    else                 asm volatile("s_waitcnt vmcnt(0)"  ::: "memory");
    __builtin_amdgcn_s_barrier();          // ready: every wave passed its wait
    asm volatile("" ::: "memory");

    const int base = (t & 3) * (BM * BK);
    bf16x8 bfr[4], af0[4], af1[4];
#pragma unroll
    for (int j = 0; j < 4; ++j)
      bfr[j] = *(const bf16x8*)&Bs[base + bOff + j * 16 * BK];
#pragma unroll
    for (int i = 0; i < 4; ++i)
      af0[i] = *(const bf16x8*)&As[base + aOff + i * 16 * BK];

    __builtin_amdgcn_s_setprio(1);
#pragma unroll
    for (int i = 0; i < 4; ++i)
#pragma unroll
      for (int j = 0; j < 4; ++j)
        acc[i][j] = __builtin_amdgcn_mfma_f32_16x16x32_bf16(
            af0[i], bfr[j], acc[i][j], 0, 0, 0);
    __builtin_amdgcn_s_setprio(0);

#pragma unroll
    for (int i = 0; i < 4; ++i)
      af1[i] = *(const bf16x8*)&As[base + aOff + (4 + i) * 16 * BK];

    __builtin_amdgcn_s_setprio(1);
#pragma unroll
    for (int i = 0; i < 4; ++i)
#pragma unroll
      for (int j = 0; j < 4; ++j)
        acc[4 + i][j] = __builtin_amdgcn_mfma_f32_16x16x32_bf16(
            af1[i], bfr[j], acc[4 + i][j], 0, 0, 0);
    __builtin_amdgcn_s_setprio(0);

    asm volatile("" ::: "memory");
    __builtin_amdgcn_s_barrier();          // done: ring slot t&3 reusable
  }

  // epilogue: C/D layout col = lane&15, row = quad*4 + reg
  float bv[4];
#pragma unroll
  for (int j = 0; j < 4; ++j) bv[j] = bias[n0 + wn * 64 + j * 16 + r];
#pragma unroll
  for (int i = 0; i < 8; ++i) {
    int mbase = m0 + wm * 128 + i * 16 + q * 4;
#pragma unroll
    for (int e = 0; e < 4; ++e) {
      float* crow = C + (size_t)(mbase + e) * N + n0 + wn * 64 + r;
#pragma unroll
      for (int j = 0; j < 4; ++j)
        crow[j * 16] = acc[i][j][e] + bv[j];
    }
  }
}

// ---------------- correctness fallback ----------------
__global__ __launch_bounds__(256) void naive_kernel(
    const float* __restrict__ x, const int* __restrict__ wq,
    const float* __restrict__ scale, const float* __restrict__ zp,
    const float* __restrict__ bias, float* __restrict__ out,
    int M, int N, int K, int G) {
  int idx = blockIdx.x * 256 + threadIdx.x;
  if (idx >= M * N) return;
  int m = idx / N, n = idx % N;
  const float* xr = x + (size_t)m * K;
  const int* wr = wq + (size_t)n * K;
  int ng = K / G;
  float acc = 0.f;
  for (int g = 0; g < ng; ++g) {
    float s = scale[(size_t)n * ng + g];
    float b = -zp[(size_t)n * ng + g] * s;
    for (int k = 0; k < G; ++k)
      acc += xr[g * G + k] * ((float)wr[g * G + k] * s + b);
  }
  out[idx] = acc + bias[n];
}

extern "C" void kernel_launch(void* const* d_in, const int* in_sizes, int n_in,
                              void* d_out, int out_size, void* d_ws, size_t ws_size,
                              hipStream_t stream) {
  const float* x     = (const float*)d_in[0];
  const int*   wq    = (const int*)d_in[1];
  const float* scale = (const float*)d_in[2];
  const float* zp    = (const float*)d_in[3];
  const float* bias  = (const float*)d_in[4];
  float* out = (float*)d_out;

  const int N  = in_sizes[4];
  const int K  = in_sizes[1] / N;
  const int ng = in_sizes[2] / N;
  const int G  = K / ng;
  const int M  = in_sizes[0] / K;

  size_t xb_bytes = (size_t)M * K * 2;
  size_t wb_bytes = (size_t)N * K * 2;
  bool divisible = (M % BM == 0) && (N % BN == 0) && (K % BK == 0);
  if (ws_size < xb_bytes + wb_bytes || !divisible) {
    int total = M * N;
    naive_kernel<<<dim3((total + 255) / 256), dim3(256), 0, stream>>>(
        x, wq, scale, zp, bias, out, M, N, K, G);
    return;
  }

  unsigned short* xb = (unsigned short*)d_ws;
  unsigned short* wb = (unsigned short*)((char*)d_ws + xb_bytes);

  int xchunks = M * K / 4;
  int wchunks = N * K / 4;
  int xblocks = (xchunks + 255) / 256;
  int wblocks = (wchunks + 255) / 256;
  prep_kernel<<<dim3(xblocks + wblocks), dim3(256), 0, stream>>>(
      x, xb, xchunks, wq, scale, zp, wb, wchunks, K, G);

  dim3 grid((M / BM) * (N / BN));
  gemm_bt_kernel<<<grid, dim3(512), 0, stream>>>(xb, wb, bias, out, M, N, K);
}

// Round 2
// 548.992 us; speedup vs baseline: 1.1330x; 1.1330x over previous
//
#include <hip/hip_runtime.h>
#include <stdint.h>

// out = x @ dequant(W)^T + bias
// x: [M,K] fp32 (M=B*S=8192), W_q: [N,K] int32 codes in [0,4),
// scale/zp: [N,K/G] fp32 (G=64), bias: [N] fp32, out: [M,N] fp32.
//
// R4: faithful m201-style fine-phase schedule. 256x256 tile, TK=64 split as
// two k32 half-tiles (256 rows x 32 cols = 16 KB staging unit). Per tile:
// 2 phases, each {stage half-tile, vmcnt(6), s_barrier, 8 ds_read_b128,
// 16 MFMA, stage half-tile, 4 ds_read, 16 MFMA} with setprio around MFMA
// clusters. One barrier per 32 MFMA; stages interleaved inside compute
// (m196's proven lever). All stages write parity t+1, all reads parity t
// -> WAR-free; RAW via vmcnt+barrier. R2's zero-conflict chunk swizzle
// (c ^= (row>>1)&3 on 64B rows) on both write (pre-swizzled global src)
// and read sides. XCD-bijective block swizzle.

typedef __attribute__((ext_vector_type(4))) float  f32x4;
typedef __attribute__((ext_vector_type(4))) int    i32x4;
typedef __attribute__((ext_vector_type(8))) __bf16 bf16x8;
typedef __attribute__((ext_vector_type(4))) unsigned short u16x4;

__device__ __forceinline__ unsigned short f2bf(float f) {
  unsigned u = __builtin_bit_cast(unsigned, f);
  u += 0x7fffu + ((u >> 16) & 1u);   // round-to-nearest-even
  return (unsigned short)(u >> 16);
}

__device__ __forceinline__ void async16(const void* g, void* l) {
  __builtin_amdgcn_global_load_lds(
      (const __attribute__((address_space(1))) unsigned int*)g,
      (__attribute__((address_space(3))) unsigned int*)l, 16, 0, 0);
}

// ---------------- fused prepass: x->bf16 and dequant W->bf16 ----------------
__global__ __launch_bounds__(256) void prep_kernel(
    const float* __restrict__ x, unsigned short* __restrict__ xb, int xchunks,
    const int* __restrict__ wq, const float* __restrict__ scale,
    const float* __restrict__ zp, unsigned short* __restrict__ wb,
    int wchunks, int K, int G) {
  int xblocks = (xchunks + 255) >> 8;
  if ((int)blockIdx.x < xblocks) {
    int i = blockIdx.x * 256 + threadIdx.x;
    if (i >= xchunks) return;
    f32x4 a = ((const f32x4*)x)[i];
    u16x4 o;
    o[0] = f2bf(a[0]); o[1] = f2bf(a[1]); o[2] = f2bf(a[2]); o[3] = f2bf(a[3]);
    *(u16x4*)(xb + (size_t)i * 4) = o;
  } else {
    int i = (blockIdx.x - xblocks) * 256 + threadIdx.x;
    if (i >= wchunks) return;
    int k4 = i * 4;
    int n = k4 / K, kk = k4 % K;
    int ng = K / G;
    int g = kk / G;
    float s = scale[(size_t)n * ng + g];
    float b = -zp[(size_t)n * ng + g] * s;   // w = q*s + b
    i32x4 qv = ((const i32x4*)wq)[i];
    u16x4 o;
    o[0] = f2bf((float)qv[0] * s + b); o[1] = f2bf((float)qv[1] * s + b);
    o[2] = f2bf((float)qv[2] * s + b); o[3] = f2bf((float)qv[3] * s + b);
    *(u16x4*)(wb + (size_t)i * 4) = o;
  }
}

// ---------------- main GEMM: C[M,N] = A[M,K] * B[N,K]^T + bias ----------------
#define BM 256
#define BN 256
#define TK 64            // K per tile = two k32 half-tiles
#define REG 8192         // elems per half-tile region: 256 rows * 32 cols

__global__ __launch_bounds__(512, 2) void gemm_bt_kernel(
    const unsigned short* __restrict__ A,   // M x K bf16
    const unsigned short* __restrict__ B,   // N x K bf16
    const float* __restrict__ bias,
    float* __restrict__ C, int M, int N, int K) {
  // [parity][khalf] 16 KB regions: 64 KB per operand, 128 KB total.
  __shared__ unsigned short As[4 * REG];
  __shared__ unsigned short Bs[4 * REG];

  const int tid  = threadIdx.x;
  const int lane = tid & 63;
  const int wave = tid >> 6;                // 8 waves: 2 (M) x 4 (N)
  const int wm = wave >> 2, wn = wave & 3;  // wave tile: 128 (M) x 64 (N)
  const int q = lane >> 4, r = lane & 15;   // MFMA k-group / row-in-16

  // XCD-aware bijective swizzle (nwg % 8 == 0).
  int id = blockIdx.x;
  {
    int nwg = gridDim.x;
    if ((nwg & 7) == 0) id = (id & 7) * (nwg >> 3) + (id >> 3);
  }
  const int nbx = N / BN;
  const int m0 = (id / nbx) * BM;
  const int n0 = (id % nbx) * BN;

  // Staging: thread tid owns LDS (row = tid>>2 within 128-row shot,
  // chunk = tid&3) of a half-tile; global source pre-swizzled so stored
  // chunk s of row holds global chunk s ^ ((row>>1)&3).
  const int srow = tid >> 2;                      // 0..127
  const int gch  = (tid & 3) ^ ((tid >> 3) & 3);  // (tid&3) ^ ((srow>>1)&3)
  const unsigned short* aG = A + (size_t)(m0 + srow) * K + gch * 8;
  const unsigned short* bG = B + (size_t)(n0 + srow) * K + gch * 8;
  const size_t rb = (size_t)128 * K;              // shot-1 row offset

  unsigned short* aS = As + tid * 8;
  unsigned short* bS = Bs + tid * 8;

  // Read side: global chunk q of row R lives at stored chunk q ^ ((R>>1)&3);
  // frag rows are 16-aligned + r, so key = (r>>1)&3 (const per lane).
  const int qc8 = (q ^ ((r >> 1) & 3)) * 8;
  const unsigned short* aRd = As + (wm * 128 + r) * 32 + qc8;  // + mi*512
  const unsigned short* bRd = Bs + (wn * 64  + r) * 32 + qc8;  // + nj*512

  f32x4 acc[8][4] = {};
  const int NT = K / TK;

  // One half-tile stage = 2 global_load_lds per thread (128 rows per shot).
#define STG(S, G, par, kh, kk) { \
    unsigned short* l = (S) + ((par) * 2 + (kh)) * REG; \
    async16((G) + (kk) + (kh) * 32, l); \
    async16((G) + rb + (kk) + (kh) * 32, l + 4096); }

  // Prologue: tile 0's 4 half-tiles, FIFO order A.k0, B.k0, A.k1, B.k1.
  STG(aS, aG, 0, 0, 0) STG(bS, bG, 0, 0, 0)
  STG(aS, aG, 0, 1, 0) STG(bS, bG, 0, 1, 0)

#pragma unroll 1
  for (int t = 0; t < NT; ++t) {
    const int par = t & 1, nxt = par ^ 1;
    const int kk1 = (t + 1) * TK;
    const bool pf = (t + 1 < NT);

    // ================= phase 0: k-half 0 =================
    if (pf) STG(aS, aG, nxt, 0, kk1)
    // FIFO: drain {A.k0(t), B.k0(t)}; leave {A.k1(t), B.k1(t), A.k0(t+1)}.
    if (pf) asm volatile("s_waitcnt vmcnt(6)" ::: "memory");
    else    asm volatile("s_waitcnt vmcnt(4)" ::: "memory");
    __builtin_amdgcn_s_barrier();
    asm volatile("" ::: "memory");
    {
      const unsigned short* a0 = aRd + par * 2 * REG;
      const unsigned short* b0 = bRd + par * 2 * REG;
      bf16x8 bf[4], af[4];
#pragma unroll
      for (int j = 0; j < 4; ++j) bf[j] = *(const bf16x8*)&b0[j * 512];
#pragma unroll
      for (int i = 0; i < 4; ++i) af[i] = *(const bf16x8*)&a0[i * 512];
      __builtin_amdgcn_s_setprio(1);
#pragma unroll
      for (int i = 0; i < 4; ++i)
#pragma unroll
        for (int j = 0; j < 4; ++j)
          acc[i][j] = __builtin_amdgcn_mfma_f32_16x16x32_bf16(
              af[i], bf[j], acc[i][j], 0, 0, 0);
      __builtin_amdgcn_s_setprio(0);
      if (pf) STG(bS, bG, nxt, 0, kk1)
#pragma unroll
      for (int i = 0; i < 4; ++i) af[i] = *(const bf16x8*)&a0[(4 + i) * 512];
      __builtin_amdgcn_s_setprio(1);
#pragma unroll
      for (int i = 0; i < 4; ++i)
#pragma unroll
        for (int j = 0; j < 4; ++j)
          acc[4 + i][j] = __builtin_amdgcn_mfma_f32_16x16x32_bf16(
              af[i], bf[j], acc[4 + i][j], 0, 0, 0);
      __builtin_amdgcn_s_setprio(0);
    }

    // ================= phase 1: k-half 1 =================
    if (pf) STG(aS, aG, nxt, 1, kk1)
    // FIFO: drain {A.k1(t), B.k1(t)}; leave {A.k0/B.k0/A.k1 of t+1}.
    if (pf) asm volatile("s_waitcnt vmcnt(6)" ::: "memory");
    else    asm volatile("s_waitcnt vmcnt(0)" ::: "memory");
    __builtin_amdgcn_s_barrier();
    asm volatile("" ::: "memory");
    {
      const unsigned short* a1 = aRd + (par * 2 + 1) * REG;
      const unsigned short* b1 = bRd + (par * 2 + 1) * REG;
      bf16x8 bf[4], af[4];
#pragma unroll
      for (int j = 0; j < 4; ++j) bf[j] = *(const bf16x8*)&b1[j * 512];
#pragma unroll
      for (int i = 0; i < 4; ++i) af[i] = *(const bf16x8*)&a1[i * 512];
      __builtin_amdgcn_s_setprio(1);
#pragma unroll
      for (int i = 0; i < 4; ++i)
#pragma unroll
        for (int j = 0; j < 4; ++j)
          acc[i][j] = __builtin_amdgcn_mfma_f32_16x16x32_bf16(
              af[i], bf[j], acc[i][j], 0, 0, 0);
      __builtin_amdgcn_s_setprio(0);
      if (pf) STG(bS, bG, nxt, 1, kk1)
#pragma unroll
      for (int i = 0; i < 4; ++i) af[i] = *(const bf16x8*)&a1[(4 + i) * 512];
      __builtin_amdgcn_s_setprio(1);
#pragma unroll
      for (int i = 0; i < 4; ++i)
#pragma unroll
        for (int j = 0; j < 4; ++j)
          acc[4 + i][j] = __builtin_amdgcn_mfma_f32_16x16x32_bf16(
              af[i], bf[j], acc[4 + i][j], 0, 0, 0);
      __builtin_amdgcn_s_setprio(0);
    }
  }

  // epilogue: C/D layout col = lane&15, row = quad*4 + reg
  float bv[4];
#pragma unroll
  for (int j = 0; j < 4; ++j) bv[j] = bias[n0 + wn * 64 + j * 16 + r];
#pragma unroll
  for (int i = 0; i < 8; ++i) {
    int mbase = m0 + wm * 128 + i * 16 + q * 4;
#pragma unroll
    for (int e = 0; e < 4; ++e) {
      float* crow = C + (size_t)(mbase + e) * N + n0 + wn * 64 + r;
#pragma unroll
      for (int j = 0; j < 4; ++j)
        crow[j * 16] = acc[i][j][e] + bv[j];
    }
  }
}

// ---------------- correctness fallback ----------------
__global__ __launch_bounds__(256) void naive_kernel(
    const float* __restrict__ x, const int* __restrict__ wq,
    const float* __restrict__ scale, const float* __restrict__ zp,
    const float* __restrict__ bias, float* __restrict__ out,
    int M, int N, int K, int G) {
  int idx = blockIdx.x * 256 + threadIdx.x;
  if (idx >= M * N) return;
  int m = idx / N, n = idx % N;
  const float* xr = x + (size_t)m * K;
  const int* wr = wq + (size_t)n * K;
  int ng = K / G;
  float acc = 0.f;
  for (int g = 0; g < ng; ++g) {
    float s = scale[(size_t)n * ng + g];
    float b = -zp[(size_t)n * ng + g] * s;
    for (int k = 0; k < G; ++k)
      acc += xr[g * G + k] * ((float)wr[g * G + k] * s + b);
  }
  out[idx] = acc + bias[n];
}

extern "C" void kernel_launch(void* const* d_in, const int* in_sizes, int n_in,
                              void* d_out, int out_size, void* d_ws, size_t ws_size,
                              hipStream_t stream) {
  const float* x     = (const float*)d_in[0];
  const int*   wq    = (const int*)d_in[1];
  const float* scale = (const float*)d_in[2];
  const float* zp    = (const float*)d_in[3];
  const float* bias  = (const float*)d_in[4];
  float* out = (float*)d_out;

  const int N  = in_sizes[4];
  const int K  = in_sizes[1] / N;
  const int ng = in_sizes[2] / N;
  const int G  = K / ng;
  const int M  = in_sizes[0] / K;

  size_t xb_bytes = (size_t)M * K * 2;
  size_t wb_bytes = (size_t)N * K * 2;
  bool divisible = (M % BM == 0) && (N % BN == 0) && (K % TK == 0);
  if (ws_size < xb_bytes + wb_bytes || !divisible) {
    int total = M * N;
    naive_kernel<<<dim3((total + 255) / 256), dim3(256), 0, stream>>>(
        x, wq, scale, zp, bias, out, M, N, K, G);
    return;
  }

  unsigned short* xb = (unsigned short*)d_ws;
  unsigned short* wb = (unsigned short*)((char*)d_ws + xb_bytes);

  int xchunks = M * K / 4;
  int wchunks = N * K / 4;
  int xblocks = (xchunks + 255) / 256;
  int wblocks = (wchunks + 255) / 256;
  prep_kernel<<<dim3(xblocks + wblocks), dim3(256), 0, stream>>>(
      x, xb, xchunks, wq, scale, zp, wb, wchunks, K, G);

  dim3 grid((M / BM) * (N / BN));
  gemm_bt_kernel<<<grid, dim3(512), 0, stream>>>(xb, wb, bias, out, M, N, K);
}